// Round 1
// baseline (1349.094 us; speedup 1.0000x reference)
//
#include <hip/hip_runtime.h>
#include <math.h>

// Problem constants (fixed by setup_inputs)
#define FEATN 128
#define NRBF  20
#define NCG   2000
#define CUTF  5.0f
#define PI_F  3.14159265358979323846f

// LDS row stride in bf16 units: 128 + 8 pad (16B-aligned, breaks bank conflicts)
#define LSTR 136

typedef __attribute__((ext_vector_type(8))) short bf16x8;
typedef __attribute__((ext_vector_type(4))) float f32x4;

__device__ inline unsigned short f2bf(float x) {
    unsigned int u = __float_as_uint(x);
    u += 0x7fffu + ((u >> 16) & 1u);
    return (unsigned short)(u >> 16);
}

// ---------------- weight packing ----------------
// B-fragment layout for mfma_f32_16x16x32_bf16:
//   lane holds B[k][n] with n = nt*16 + (lane&15), k = kt*32 + (lane>>4)*8 + j, j=0..7
// packed flat: (((kt*NT + nt)*64 + lane)*8 + j)
#define W1P_ELEMS (4*8*64*8)    // 16384
#define W2P_ELEMS (4*24*64*8)   // 49152
#define WRP_ELEMS (24*64*8)     // 12288  (K padded 20->32, single kt)

__global__ void pack_weights(const float* __restrict__ W1,
                             const float* __restrict__ W2,
                             const float* __restrict__ Wr,
                             short* __restrict__ W1p,
                             short* __restrict__ W2p,
                             short* __restrict__ Wrp) {
    int t = blockIdx.x * blockDim.x + threadIdx.x;
    if (t < W1P_ELEMS) {
        int j = t & 7, lane = (t >> 3) & 63, tile = t >> 9; // tile = kt*8+nt
        int nt = tile & 7, kt = tile >> 3;
        int k = kt * 32 + (lane >> 4) * 8 + j;
        int n = nt * 16 + (lane & 15);
        W1p[t] = (short)f2bf(W1[k * 128 + n]);
        return;
    }
    t -= W1P_ELEMS;
    if (t < W2P_ELEMS) {
        int j = t & 7, lane = (t >> 3) & 63, tile = t >> 9; // tile = kt*24+nt
        int nt = tile % 24, kt = tile / 24;
        int k = kt * 32 + (lane >> 4) * 8 + j;
        int n = nt * 16 + (lane & 15);
        W2p[t] = (short)f2bf(W2[k * 384 + n]);
        return;
    }
    t -= W2P_ELEMS;
    if (t < WRP_ELEMS) {
        int j = t & 7, lane = (t >> 3) & 63, nt = t >> 9; // 0..23
        int k = (lane >> 4) * 8 + j;
        int n = nt * 16 + (lane & 15);
        float v = (k < NRBF) ? Wr[k * 384 + n] : 0.0f;
        Wrp[t] = (short)f2bf(v);
    }
}

// ---------------- segment counts ----------------
__global__ void count_kernel(const int* __restrict__ mapping,
                             float* __restrict__ counts, int E) {
    int t = blockIdx.x * blockDim.x + threadIdx.x;
    if (t < E) atomicAdd(&counts[mapping[t]], 1.0f);
}

// ---------------- main fused kernel ----------------
// 64 edges/block, 4 waves; wave w handles edges [w*16, w*16+16)
__global__ __launch_bounds__(256) void
main_kernel(const float* __restrict__ s_i, const float* __restrict__ v_i,
            const float* __restrict__ r_iI, const float* __restrict__ b1,
            const float* __restrict__ b2, const float* __restrict__ br,
            const int* __restrict__ mapping,
            const short* __restrict__ W1p, const short* __restrict__ W2p,
            const short* __restrict__ Wrp,
            float* __restrict__ acc_s, float* __restrict__ acc_v) {
    __shared__ __align__(16) short lds_s[64 * LSTR];
    __shared__ __align__(16) short lds_h[64 * LSTR];
    __shared__ float lds_dist[64];
    __shared__ float lds_env[64];
    __shared__ float lds_unit[64][3];
    __shared__ int   lds_seg[64];

    const int tid  = threadIdx.x;
    const int lane = tid & 63;
    const int w    = tid >> 6;       // wave 0..3
    const int lq   = lane >> 4;      // quad 0..3
    const int lc   = lane & 15;
    const int edge0 = blockIdx.x * 64;

    // ---- Phase 0: stage s tile (fp32 -> bf16) into LDS, coalesced float4 ----
    {
        int row = tid >> 2;          // 0..63
        int q   = tid & 3;
        const float4* src = reinterpret_cast<const float4*>(
            s_i + (size_t)(edge0 + row) * FEATN + q * 32);
        short* dst = lds_s + row * LSTR + q * 32;
#pragma unroll
        for (int c = 0; c < 8; ++c) {
            float4 v = src[c];
            unsigned int p0 = (unsigned int)f2bf(v.x) | ((unsigned int)f2bf(v.y) << 16);
            unsigned int p1 = (unsigned int)f2bf(v.z) | ((unsigned int)f2bf(v.w) << 16);
            *reinterpret_cast<uint2*>(dst + c * 4) = make_uint2(p0, p1);
        }
    }
    // ---- Phase 0b: per-edge geometry ----
    if (tid < 64) {
        int g = edge0 + tid;
        float x = r_iI[g * 3 + 0], y = r_iI[g * 3 + 1], z = r_iI[g * 3 + 2];
        float d = sqrtf(x * x + y * y + z * z + 3e-8f);
        lds_dist[tid] = d;
        float inv_d = 1.0f / d;
        lds_unit[tid][0] = x * inv_d;
        lds_unit[tid][1] = y * inv_d;
        lds_unit[tid][2] = z * inv_d;
        lds_env[tid] = (d < CUTF) ? 0.5f * (cosf(PI_F * d / CUTF) + 1.0f) : 0.0f;
        lds_seg[tid] = mapping[g];
    }
    __syncthreads();

    // ---- Phase 1: GEMM1  H = silu(S @ W1 + b1) ----
    bf16x8 a1[4];
#pragma unroll
    for (int kt = 0; kt < 4; ++kt)
        a1[kt] = *reinterpret_cast<const bf16x8*>(
            lds_s + (w * 16 + lc) * LSTR + kt * 32 + lq * 8);

    const bf16x8* W1f = reinterpret_cast<const bf16x8*>(W1p);
#pragma unroll
    for (int nt = 0; nt < 8; ++nt) {
        f32x4 acc = {0.f, 0.f, 0.f, 0.f};
#pragma unroll
        for (int kt = 0; kt < 4; ++kt)
            acc = __builtin_amdgcn_mfma_f32_16x16x32_bf16(
                a1[kt], W1f[(kt * 8 + nt) * 64 + lane], acc, 0, 0, 0);
        float b1v = b1[nt * 16 + lc];
#pragma unroll
        for (int i = 0; i < 4; ++i) {
            float x = acc[i] + b1v;
            float h = x / (1.0f + __expf(-x));
            lds_h[(w * 16 + lq * 4 + i) * LSTR + nt * 16 + lc] = (short)f2bf(h);
        }
    }
    __syncthreads();

    // ---- Phase 2: GEMM2 + rbf GEMM + epilogue ----
    bf16x8 a2[4];
#pragma unroll
    for (int kt = 0; kt < 4; ++kt)
        a2[kt] = *reinterpret_cast<const bf16x8*>(
            lds_h + (w * 16 + lc) * LSTR + kt * 32 + lq * 8);

    // rbf A-fragment: edge m = lane&15, k = lq*8+j  (k>=20 zero-padded)
    bf16x8 rb;
    {
        float d = lds_dist[w * 16 + lc];
        float inv_d = 1.0f / d;
#pragma unroll
        for (int j = 0; j < 8; ++j) {
            int k = lq * 8 + j;
            float v = 0.0f;
            if (k < NRBF) v = sinf((float)(k + 1) * PI_F * d / CUTF) * inv_d;
            rb[j] = (short)f2bf(v);
        }
    }

    // per-accumulator-element geometry: edge = w*16 + lq*4 + i
    int   segi[4]; float envi[4], ux[4], uy[4], uz[4];
#pragma unroll
    for (int i = 0; i < 4; ++i) {
        int e = w * 16 + lq * 4 + i;
        segi[i] = lds_seg[e];
        envi[i] = lds_env[e];
        ux[i] = lds_unit[e][0]; uy[i] = lds_unit[e][1]; uz[i] = lds_unit[e][2];
    }

    const bf16x8* W2f = reinterpret_cast<const bf16x8*>(W2p);
    const bf16x8* Wrf = reinterpret_cast<const bf16x8*>(Wrp);

    for (int ft = 0; ft < 8; ++ft) {   // feature tile: channels c0=ft, c1=ft+8, c2=ft+16
        f32x4 acc0 = {0.f,0.f,0.f,0.f}, acc1 = {0.f,0.f,0.f,0.f}, acc2 = {0.f,0.f,0.f,0.f};
#pragma unroll
        for (int kt = 0; kt < 4; ++kt) {
            bf16x8 a = a2[kt];
            acc0 = __builtin_amdgcn_mfma_f32_16x16x32_bf16(a, W2f[(kt * 24 + ft     ) * 64 + lane], acc0, 0, 0, 0);
            acc1 = __builtin_amdgcn_mfma_f32_16x16x32_bf16(a, W2f[(kt * 24 + ft +  8) * 64 + lane], acc1, 0, 0, 0);
            acc2 = __builtin_amdgcn_mfma_f32_16x16x32_bf16(a, W2f[(kt * 24 + ft + 16) * 64 + lane], acc2, 0, 0, 0);
        }
        f32x4 z4 = {0.f,0.f,0.f,0.f};
        f32x4 wa0 = __builtin_amdgcn_mfma_f32_16x16x32_bf16(rb, Wrf[(ft     ) * 64 + lane], z4, 0, 0, 0);
        f32x4 wa1 = __builtin_amdgcn_mfma_f32_16x16x32_bf16(rb, Wrf[(ft +  8) * 64 + lane], z4, 0, 0, 0);
        f32x4 wa2 = __builtin_amdgcn_mfma_f32_16x16x32_bf16(rb, Wrf[(ft + 16) * 64 + lane], z4, 0, 0, 0);

        int f = ft * 16 + lc;
        float b2v0 = b2[f], b2v1 = b2[128 + f], b2v2 = b2[256 + f];
        float brv0 = br[f], brv1 = br[128 + f], brv2 = br[256 + f];

#pragma unroll
        for (int i = 0; i < 4; ++i) {
            float phi0 = acc0[i] + b2v0;
            float phi1 = acc1[i] + b2v1;
            float phi2 = acc2[i] + b2v2;
            float w0 = (wa0[i] + brv0) * envi[i];
            float w1 = (wa1[i] + brv1) * envi[i];
            float w2 = (wa2[i] + brv2) * envi[i];
            float inv0 = phi0 * w0;
            float inv1 = phi1 * w1;
            float inv2 = phi2 * w2;

            // delta_s
            atomicAdd(&acc_s[(size_t)segi[i] * 128 + f], inv1);
            // delta_v = inv2*unit + inv0*v_i
            const float* vp = v_i + (size_t)(edge0 + w * 16 + lq * 4 + i) * 384 + f * 3;
            float* ap = acc_v + (size_t)segi[i] * 384 + f * 3;
            atomicAdd(ap + 0, inv2 * ux[i] + inv0 * vp[0]);
            atomicAdd(ap + 1, inv2 * uy[i] + inv0 * vp[1]);
            atomicAdd(ap + 2, inv2 * uz[i] + inv0 * vp[2]);
        }
    }
}

// ---------------- finalize: mean + write out ----------------
__global__ void finalize_kernel(const float* __restrict__ acc_s,
                                const float* __restrict__ acc_v,
                                const float* __restrict__ counts,
                                float* __restrict__ out) {
    int t = blockIdx.x * blockDim.x + threadIdx.x;
    const int NS = NCG * 128;
    if (t < NS) {
        int seg = t >> 7;
        out[t] = acc_s[t] / fmaxf(counts[seg], 1.0f);
    } else {
        int t2 = t - NS;
        int seg = t2 / 384;
        out[t] = acc_v[t2] / fmaxf(counts[seg], 1.0f);
    }
}

extern "C" void kernel_launch(void* const* d_in, const int* in_sizes, int n_in,
                              void* d_out, int out_size, void* d_ws, size_t ws_size,
                              hipStream_t stream) {
    const float* s_i  = (const float*)d_in[0];
    const float* v_i  = (const float*)d_in[1];
    const float* r_iI = (const float*)d_in[2];
    const float* W1   = (const float*)d_in[3];
    const float* b1   = (const float*)d_in[4];
    const float* W2   = (const float*)d_in[5];
    const float* b2   = (const float*)d_in[6];
    const float* Wr   = (const float*)d_in[7];
    const float* br   = (const float*)d_in[8];
    const int* mapping = (const int*)d_in[9];
    // d_in[10] = num_cg (compile-time NCG=2000)

    const int E = in_sizes[0] / FEATN;   // 200000

    char* ws = (char*)d_ws;
    float* acc_s  = (float*)(ws + 0);          // 2000*128*4 = 1,024,000
    float* acc_v  = (float*)(ws + 1024000);    // 2000*384*4 = 3,072,000
    float* counts = (float*)(ws + 4096000);    // 2000*4     = 8,000
    short* W1p    = (short*)(ws + 4104192);    // 32,768 B
    short* W2p    = (short*)(ws + 4136960);    // 98,304 B
    short* Wrp    = (short*)(ws + 4235264);    // 24,576 B

    hipMemsetAsync(ws, 0, 4104000, stream);
    pack_weights<<<(W1P_ELEMS + W2P_ELEMS + WRP_ELEMS) / 256, 256, 0, stream>>>(
        W1, W2, Wr, W1p, W2p, Wrp);
    count_kernel<<<(E + 255) / 256, 256, 0, stream>>>(mapping, counts, E);
    main_kernel<<<E / 64, 256, 0, stream>>>(s_i, v_i, r_iI, b1, b2, br, mapping,
                                            W1p, W2p, Wrp, acc_s, acc_v);
    finalize_kernel<<<(NCG * 512) / 256, 256, 0, stream>>>(acc_s, acc_v, counts,
                                                           (float*)d_out);
}

// Round 2
// 1287.810 us; speedup vs baseline: 1.0476x; 1.0476x over previous
//
#include <hip/hip_runtime.h>
#include <math.h>

// Problem constants (fixed by setup_inputs)
#define FEATN 128
#define NRBF  20
#define NCG   2000
#define CUTF  5.0f
#define PI_F  3.14159265358979323846f

// LDS row stride in bf16 units: 128 + 8 pad (16B-aligned, breaks bank conflicts)
#define LSTR 136

typedef __attribute__((ext_vector_type(8))) short bf16x8;
typedef __attribute__((ext_vector_type(4))) float f32x4;

__device__ inline unsigned short f2bf(float x) {
    unsigned int u = __float_as_uint(x);
    u += 0x7fffu + ((u >> 16) & 1u);
    return (unsigned short)(u >> 16);
}

// ---------------- weight packing ----------------
// B-fragment layout for mfma_f32_16x16x32_bf16:
//   lane holds B[k][n] with n = nt*16 + (lane&15), k = kt*32 + (lane>>4)*8 + j, j=0..7
// packed flat: (((kt*NT + nt)*64 + lane)*8 + j)
#define W1P_ELEMS (4*8*64*8)    // 16384
#define W2P_ELEMS (4*24*64*8)   // 49152
#define WRP_ELEMS (24*64*8)     // 12288  (K padded 20->32, single kt)

__global__ void pack_weights(const float* __restrict__ W1,
                             const float* __restrict__ W2,
                             const float* __restrict__ Wr,
                             short* __restrict__ W1p,
                             short* __restrict__ W2p,
                             short* __restrict__ Wrp) {
    int t = blockIdx.x * blockDim.x + threadIdx.x;
    if (t < W1P_ELEMS) {
        int j = t & 7, lane = (t >> 3) & 63, tile = t >> 9; // tile = kt*8+nt
        int nt = tile & 7, kt = tile >> 3;
        int k = kt * 32 + (lane >> 4) * 8 + j;
        int n = nt * 16 + (lane & 15);
        W1p[t] = (short)f2bf(W1[k * 128 + n]);
        return;
    }
    t -= W1P_ELEMS;
    if (t < W2P_ELEMS) {
        int j = t & 7, lane = (t >> 3) & 63, tile = t >> 9; // tile = kt*24+nt
        int nt = tile % 24, kt = tile / 24;
        int k = kt * 32 + (lane >> 4) * 8 + j;
        int n = nt * 16 + (lane & 15);
        W2p[t] = (short)f2bf(W2[k * 384 + n]);
        return;
    }
    t -= W2P_ELEMS;
    if (t < WRP_ELEMS) {
        int j = t & 7, lane = (t >> 3) & 63, nt = t >> 9; // 0..23
        int k = (lane >> 4) * 8 + j;
        int n = nt * 16 + (lane & 15);
        float v = (k < NRBF) ? Wr[k * 384 + n] : 0.0f;
        Wrp[t] = (short)f2bf(v);
    }
}

// ---------------- counting sort by segment ----------------
__global__ void hist_kernel(const int* __restrict__ mapping,
                            int* __restrict__ counts, int E) {
    int t = blockIdx.x * blockDim.x + threadIdx.x;
    if (t < E) atomicAdd(&counts[mapping[t]], 1);
}

// one block of 64 threads; 64*32 = 2048 >= NCG
__global__ void scan_kernel(const int* __restrict__ counts,
                            int* __restrict__ start,
                            int* __restrict__ cursor) {
    int lane = threadIdx.x;          // 0..63
    int base = lane * 32;
    int loc[32];
    int s = 0;
#pragma unroll
    for (int j = 0; j < 32; ++j) {
        int idx = base + j;
        int c = (idx < NCG) ? counts[idx] : 0;
        loc[j] = s;
        s += c;
    }
    int inc = s;
#pragma unroll
    for (int off = 1; off < 64; off <<= 1) {
        int n = __shfl_up(inc, off, 64);
        if (lane >= off) inc += n;
    }
    int excl = inc - s;
#pragma unroll
    for (int j = 0; j < 32; ++j) {
        int idx = base + j;
        if (idx < NCG) {
            start[idx]  = excl + loc[j];
            cursor[idx] = excl + loc[j];
        }
    }
}

__global__ void scatter_kernel(const int* __restrict__ mapping,
                               int* __restrict__ cursor,
                               int* __restrict__ order, int E) {
    int t = blockIdx.x * blockDim.x + threadIdx.x;
    if (t < E) {
        int seg = mapping[t];
        int pos = atomicAdd(&cursor[seg], 1);
        order[pos] = t;
    }
}

// ---------------- main fused kernel: one block per segment ----------------
// 64 edges/tile, 4 waves; wave w handles edge rows [w*16, w*16+16)
__global__ __launch_bounds__(256) void
main_kernel(const float* __restrict__ s_i, const float* __restrict__ v_i,
            const float* __restrict__ r_iI, const float* __restrict__ b1,
            const float* __restrict__ b2, const float* __restrict__ br,
            const int* __restrict__ order, const int* __restrict__ start,
            const int* __restrict__ counts,
            const short* __restrict__ W1p, const short* __restrict__ W2p,
            const short* __restrict__ Wrp,
            float* __restrict__ out) {
    __shared__ __align__(16) short lds_s[64 * LSTR];
    __shared__ __align__(16) short lds_h[64 * LSTR];
    __shared__ float lds_acc[4 * 512];    // per-wave accumulators: [s:128][v:384]
    __shared__ int   lds_eid[64];
    __shared__ float lds_dist[64];
    __shared__ float lds_env[64];
    __shared__ float lds_unit[64][3];

    const int tid  = threadIdx.x;
    const int lane = tid & 63;
    const int w    = tid >> 6;       // wave 0..3
    const int lq   = lane >> 4;      // quad 0..3
    const int lc   = lane & 15;
    const int seg  = blockIdx.x;

    const int st  = start[seg];
    const int cnt = counts[seg];

    // zero per-wave accumulators
    for (int i = tid; i < 4 * 512; i += 256) lds_acc[i] = 0.0f;

    // hoist b1
    float b1v[8];
#pragma unroll
    for (int nt = 0; nt < 8; ++nt) b1v[nt] = b1[nt * 16 + lc];

    const bf16x8* W1f = reinterpret_cast<const bf16x8*>(W1p);
    const bf16x8* W2f = reinterpret_cast<const bf16x8*>(W2p);
    const bf16x8* Wrf = reinterpret_cast<const bf16x8*>(Wrp);

    const int nT = (cnt + 63) >> 6;
    for (int t = 0; t < nT; ++t) {
        const int base  = st + t * 64;
        const int valid = min(64, cnt - t * 64);

        __syncthreads();   // protect lds_s/lds_eid from previous iteration readers
        if (tid < 64) lds_eid[tid] = order[base + min(tid, valid - 1)];
        __syncthreads();

        // ---- stage s rows (gathered, fp32 -> bf16), 4 threads per row ----
        {
            int row = tid >> 2;
            int q   = tid & 3;
            int e   = lds_eid[row];
            const float4* src = reinterpret_cast<const float4*>(
                s_i + (size_t)e * FEATN + q * 32);
            short* dst = lds_s + row * LSTR + q * 32;
#pragma unroll
            for (int c = 0; c < 8; ++c) {
                float4 v = src[c];
                unsigned int p0 = (unsigned int)f2bf(v.x) | ((unsigned int)f2bf(v.y) << 16);
                unsigned int p1 = (unsigned int)f2bf(v.z) | ((unsigned int)f2bf(v.w) << 16);
                *reinterpret_cast<uint2*>(dst + c * 4) = make_uint2(p0, p1);
            }
        }
        // ---- per-edge geometry ----
        if (tid < 64) {
            int e = lds_eid[tid];
            float x = r_iI[e * 3 + 0], y = r_iI[e * 3 + 1], z = r_iI[e * 3 + 2];
            float d = sqrtf(x * x + y * y + z * z + 3e-8f);
            lds_dist[tid] = d;
            float inv_d = 1.0f / d;
            lds_unit[tid][0] = x * inv_d;
            lds_unit[tid][1] = y * inv_d;
            lds_unit[tid][2] = z * inv_d;
            float env = (d < CUTF) ? 0.5f * (cosf(PI_F * d / CUTF) + 1.0f) : 0.0f;
            lds_env[tid] = (tid < valid) ? env : 0.0f;   // mask padded rows
        }
        __syncthreads();

        // ---- GEMM1: H = silu(S @ W1 + b1) ----
        bf16x8 a1[4];
#pragma unroll
        for (int kt = 0; kt < 4; ++kt)
            a1[kt] = *reinterpret_cast<const bf16x8*>(
                lds_s + (w * 16 + lc) * LSTR + kt * 32 + lq * 8);

#pragma unroll
        for (int nt = 0; nt < 8; ++nt) {
            f32x4 acc = {0.f, 0.f, 0.f, 0.f};
#pragma unroll
            for (int kt = 0; kt < 4; ++kt)
                acc = __builtin_amdgcn_mfma_f32_16x16x32_bf16(
                    a1[kt], W1f[(kt * 8 + nt) * 64 + lane], acc, 0, 0, 0);
#pragma unroll
            for (int i = 0; i < 4; ++i) {
                float x = acc[i] + b1v[nt];
                float h = x / (1.0f + __expf(-x));
                lds_h[(w * 16 + lq * 4 + i) * LSTR + nt * 16 + lc] = (short)f2bf(h);
            }
        }
        // lds_h rows are wave-private (wave w writes & reads rows w*16..w*16+15):
        // intra-wave LDS ordering is program order — no barrier needed.

        // ---- GEMM2 A-fragments + rbf fragment ----
        bf16x8 a2[4];
#pragma unroll
        for (int kt = 0; kt < 4; ++kt)
            a2[kt] = *reinterpret_cast<const bf16x8*>(
                lds_h + (w * 16 + lc) * LSTR + kt * 32 + lq * 8);

        bf16x8 rb;
        {
            float d = lds_dist[w * 16 + lc];
            float inv_d = 1.0f / d;
#pragma unroll
            for (int j = 0; j < 8; ++j) {
                int k = lq * 8 + j;
                float v = 0.0f;
                if (k < NRBF) v = sinf((float)(k + 1) * PI_F * d / CUTF) * inv_d;
                rb[j] = (short)f2bf(v);
            }
        }

        // per-accumulator-row geometry: edge row = w*16 + lq*4 + i
        int   ei[4]; float envi[4], ux[4], uy[4], uz[4];
#pragma unroll
        for (int i = 0; i < 4; ++i) {
            int e = w * 16 + lq * 4 + i;
            ei[i]   = lds_eid[e];
            envi[i] = lds_env[e];
            ux[i] = lds_unit[e][0]; uy[i] = lds_unit[e][1]; uz[i] = lds_unit[e][2];
        }

        float* aw = lds_acc + w * 512;

#pragma unroll
        for (int ft = 0; ft < 8; ++ft) {
            f32x4 acc0 = {0.f,0.f,0.f,0.f}, acc1 = {0.f,0.f,0.f,0.f}, acc2 = {0.f,0.f,0.f,0.f};
#pragma unroll
            for (int kt = 0; kt < 4; ++kt) {
                bf16x8 a = a2[kt];
                acc0 = __builtin_amdgcn_mfma_f32_16x16x32_bf16(a, W2f[(kt * 24 + ft     ) * 64 + lane], acc0, 0, 0, 0);
                acc1 = __builtin_amdgcn_mfma_f32_16x16x32_bf16(a, W2f[(kt * 24 + ft +  8) * 64 + lane], acc1, 0, 0, 0);
                acc2 = __builtin_amdgcn_mfma_f32_16x16x32_bf16(a, W2f[(kt * 24 + ft + 16) * 64 + lane], acc2, 0, 0, 0);
            }
            f32x4 z4 = {0.f,0.f,0.f,0.f};
            f32x4 wa0 = __builtin_amdgcn_mfma_f32_16x16x32_bf16(rb, Wrf[(ft     ) * 64 + lane], z4, 0, 0, 0);
            f32x4 wa1 = __builtin_amdgcn_mfma_f32_16x16x32_bf16(rb, Wrf[(ft +  8) * 64 + lane], z4, 0, 0, 0);
            f32x4 wa2 = __builtin_amdgcn_mfma_f32_16x16x32_bf16(rb, Wrf[(ft + 16) * 64 + lane], z4, 0, 0, 0);

            int f = ft * 16 + lc;
            float b2v0 = b2[f], b2v1 = b2[128 + f], b2v2 = b2[256 + f];
            float brv0 = br[f], brv1 = br[128 + f], brv2 = br[256 + f];

            float sds = 0.f, svx = 0.f, svy = 0.f, svz = 0.f;
#pragma unroll
            for (int i = 0; i < 4; ++i) {
                float phi0 = acc0[i] + b2v0;
                float phi1 = acc1[i] + b2v1;
                float phi2 = acc2[i] + b2v2;
                float w0 = (wa0[i] + brv0) * envi[i];
                float w1 = (wa1[i] + brv1) * envi[i];
                float w2 = (wa2[i] + brv2) * envi[i];
                float inv0 = phi0 * w0;
                float inv1 = phi1 * w1;
                float inv2 = phi2 * w2;

                const float* vp = v_i + (size_t)ei[i] * 384 + f * 3;
                sds += inv1;
                svx += inv2 * ux[i] + inv0 * vp[0];
                svy += inv2 * uy[i] + inv0 * vp[1];
                svz += inv2 * uz[i] + inv0 * vp[2];
            }
            // reduce across the 4 quads (edge groups): lanes differ in lq only
            sds += __shfl_xor(sds, 16); sds += __shfl_xor(sds, 32);
            svx += __shfl_xor(svx, 16); svx += __shfl_xor(svx, 32);
            svy += __shfl_xor(svy, 16); svy += __shfl_xor(svy, 32);
            svz += __shfl_xor(svz, 16); svz += __shfl_xor(svz, 32);
            if (lq == 0) {
                aw[f]               += sds;
                aw[128 + f * 3 + 0] += svx;
                aw[128 + f * 3 + 1] += svy;
                aw[128 + f * 3 + 2] += svz;
            }
        }
    }
    __syncthreads();

    // ---- final: cross-wave reduce, mean, write out ----
    const float invc = (cnt > 0) ? (1.0f / (float)cnt) : 0.0f;
    const int NS = NCG * 128;
    for (int o = tid; o < 512; o += 256) {
        float v = lds_acc[o] + lds_acc[512 + o] + lds_acc[1024 + o] + lds_acc[1536 + o];
        v *= invc;
        if (o < 128) out[(size_t)seg * 128 + o] = v;
        else         out[NS + (size_t)seg * 384 + (o - 128)] = v;
    }
}

extern "C" void kernel_launch(void* const* d_in, const int* in_sizes, int n_in,
                              void* d_out, int out_size, void* d_ws, size_t ws_size,
                              hipStream_t stream) {
    const float* s_i  = (const float*)d_in[0];
    const float* v_i  = (const float*)d_in[1];
    const float* r_iI = (const float*)d_in[2];
    const float* W1   = (const float*)d_in[3];
    const float* b1   = (const float*)d_in[4];
    const float* W2   = (const float*)d_in[5];
    const float* b2   = (const float*)d_in[6];
    const float* Wr   = (const float*)d_in[7];
    const float* br   = (const float*)d_in[8];
    const int* mapping = (const int*)d_in[9];
    // d_in[10] = num_cg (compile-time NCG=2000)

    const int E = in_sizes[0] / FEATN;   // 200000

    char* ws = (char*)d_ws;
    int*   counts = (int*)(ws + 0);          //  8,000 B
    int*   start  = (int*)(ws + 8192);       //  8,000 B
    int*   cursor = (int*)(ws + 16384);      //  8,000 B
    int*   order  = (int*)(ws + 24576);      // 800,000 B
    short* W1p    = (short*)(ws + 829440);   // 32,768 B
    short* W2p    = (short*)(ws + 862208);   // 98,304 B
    short* Wrp    = (short*)(ws + 960512);   // 24,576 B

    hipMemsetAsync(counts, 0, NCG * sizeof(int), stream);
    pack_weights<<<(W1P_ELEMS + W2P_ELEMS + WRP_ELEMS) / 256, 256, 0, stream>>>(
        W1, W2, Wr, W1p, W2p, Wrp);
    hist_kernel<<<(E + 255) / 256, 256, 0, stream>>>(mapping, counts, E);
    scan_kernel<<<1, 64, 0, stream>>>(counts, start, cursor);
    scatter_kernel<<<(E + 255) / 256, 256, 0, stream>>>(mapping, cursor, order, E);
    main_kernel<<<NCG, 256, 0, stream>>>(s_i, v_i, r_iI, b1, b2, br,
                                         order, start, counts,
                                         W1p, W2p, Wrp, (float*)d_out);
}

// Round 3
// 812.620 us; speedup vs baseline: 1.6602x; 1.5848x over previous
//
#include <hip/hip_runtime.h>
#include <math.h>

// Problem constants (fixed by setup_inputs)
#define FEATN 128
#define NRBF  20
#define NCG   2000
#define CUTF  5.0f
#define PI_F  3.14159265358979323846f

// LDS row stride in bf16 units: 128 + 8 pad (16B-aligned, breaks bank conflicts)
#define LSTR 136

typedef __attribute__((ext_vector_type(8))) short bf16x8;
typedef __attribute__((ext_vector_type(4))) float f32x4;

__device__ inline unsigned short f2bf(float x) {
    unsigned int u = __float_as_uint(x);
    u += 0x7fffu + ((u >> 16) & 1u);
    return (unsigned short)(u >> 16);
}

// ---------------- weight packing ----------------
// B-fragment layout for mfma_f32_16x16x32_bf16:
//   lane holds B[k][n] with n = nt*16 + (lane&15), k = kt*32 + (lane>>4)*8 + j, j=0..7
// packed flat: (((kt*NT + nt)*64 + lane)*8 + j)
#define W1P_ELEMS (4*8*64*8)    // 16384
#define W2P_ELEMS (4*24*64*8)   // 49152
#define WRP_ELEMS (24*64*8)     // 12288  (K padded 20->32, single kt)

__global__ void pack_weights(const float* __restrict__ W1,
                             const float* __restrict__ W2,
                             const float* __restrict__ Wr,
                             short* __restrict__ W1p,
                             short* __restrict__ W2p,
                             short* __restrict__ Wrp) {
    int t = blockIdx.x * blockDim.x + threadIdx.x;
    if (t < W1P_ELEMS) {
        int j = t & 7, lane = (t >> 3) & 63, tile = t >> 9; // tile = kt*8+nt
        int nt = tile & 7, kt = tile >> 3;
        int k = kt * 32 + (lane >> 4) * 8 + j;
        int n = nt * 16 + (lane & 15);
        W1p[t] = (short)f2bf(W1[k * 128 + n]);
        return;
    }
    t -= W1P_ELEMS;
    if (t < W2P_ELEMS) {
        int j = t & 7, lane = (t >> 3) & 63, tile = t >> 9; // tile = kt*24+nt
        int nt = tile % 24, kt = tile / 24;
        int k = kt * 32 + (lane >> 4) * 8 + j;
        int n = nt * 16 + (lane & 15);
        W2p[t] = (short)f2bf(W2[k * 384 + n]);
        return;
    }
    t -= WRP_ELEMS ? W2P_ELEMS : W2P_ELEMS;  // (kept simple below)
    if (t < WRP_ELEMS) {
        int j = t & 7, lane = (t >> 3) & 63, nt = t >> 9; // 0..23
        int k = (lane >> 4) * 8 + j;
        int n = nt * 16 + (lane & 15);
        float v = (k < NRBF) ? Wr[k * 384 + n] : 0.0f;
        Wrp[t] = (short)f2bf(v);
    }
}

// ---------------- counting sort by segment ----------------
__global__ void hist_kernel(const int* __restrict__ mapping,
                            int* __restrict__ counts, int E) {
    int t = blockIdx.x * blockDim.x + threadIdx.x;
    if (t < E) atomicAdd(&counts[mapping[t]], 1);
}

// one block of 64 threads; 64*32 = 2048 >= NCG
__global__ void scan_kernel(const int* __restrict__ counts,
                            int* __restrict__ start,
                            int* __restrict__ cursor) {
    int lane = threadIdx.x;          // 0..63
    int base = lane * 32;
    int loc[32];
    int s = 0;
#pragma unroll
    for (int j = 0; j < 32; ++j) {
        int idx = base + j;
        int c = (idx < NCG) ? counts[idx] : 0;
        loc[j] = s;
        s += c;
    }
    int inc = s;
#pragma unroll
    for (int off = 1; off < 64; off <<= 1) {
        int n = __shfl_up(inc, off, 64);
        if (lane >= off) inc += n;
    }
    int excl = inc - s;
#pragma unroll
    for (int j = 0; j < 32; ++j) {
        int idx = base + j;
        if (idx < NCG) {
            start[idx]  = excl + loc[j];
            cursor[idx] = excl + loc[j];
        }
    }
}

__global__ void scatter_kernel(const int* __restrict__ mapping,
                               int* __restrict__ cursor,
                               int* __restrict__ order, int E) {
    int t = blockIdx.x * blockDim.x + threadIdx.x;
    if (t < E) {
        int seg = mapping[t];
        int pos = atomicAdd(&cursor[seg], 1);
        order[pos] = t;
    }
}

// ---------------- main fused kernel: one block per segment ----------------
// 64 edges/tile, 4 waves; wave w handles edge rows [w*16, w*16+16).
// lds_sh holds the S tile, then is overwritten in-place (wave-private rows)
// with the H tile — each wave loads its A1 fragments to registers first.
__global__ __launch_bounds__(256, 4) void
main_kernel(const float* __restrict__ s_i, const float* __restrict__ v_i,
            const float* __restrict__ r_iI, const float* __restrict__ b1,
            const float* __restrict__ b2, const float* __restrict__ br,
            const int* __restrict__ order, const int* __restrict__ start,
            const int* __restrict__ counts,
            const short* __restrict__ W1p, const short* __restrict__ W2p,
            const short* __restrict__ Wrp,
            float* __restrict__ out) {
    __shared__ __align__(16) short lds_sh[64 * LSTR];   // S tile, then H tile
    __shared__ float lds_acc[4 * 512];    // per-wave accumulators: [s:128][v:384]
    __shared__ int   lds_eid[64];
    __shared__ float lds_dist[64];
    __shared__ float lds_env[64];
    __shared__ float lds_unit[64][3];

    const int tid  = threadIdx.x;
    const int lane = tid & 63;
    const int w    = tid >> 6;       // wave 0..3
    const int lq   = lane >> 4;      // quad 0..3
    const int lc   = lane & 15;
    const int seg  = blockIdx.x;

    const int st  = start[seg];
    const int cnt = counts[seg];

    // zero per-wave accumulators
    for (int i = tid; i < 4 * 512; i += 256) lds_acc[i] = 0.0f;

    // hoist b1
    float b1v[8];
#pragma unroll
    for (int nt = 0; nt < 8; ++nt) b1v[nt] = b1[nt * 16 + lc];

    const bf16x8* W1f = reinterpret_cast<const bf16x8*>(W1p);
    const bf16x8* W2f = reinterpret_cast<const bf16x8*>(W2p);
    const bf16x8* Wrf = reinterpret_cast<const bf16x8*>(Wrp);

    const int nT = (cnt + 63) >> 6;
    for (int t = 0; t < nT; ++t) {
        const int base  = st + t * 64;
        const int valid = min(64, cnt - t * 64);

        __syncthreads();   // protect LDS from previous-iteration readers
        if (tid < 64) lds_eid[tid] = order[base + min(tid, valid - 1)];
        __syncthreads();

        // ---- stage s rows (gathered, fp32 -> bf16), 4 threads per row ----
        {
            int row = tid >> 2;
            int q   = tid & 3;
            int e   = lds_eid[row];
            const float4* src = reinterpret_cast<const float4*>(
                s_i + (size_t)e * FEATN + q * 32);
            short* dst = lds_sh + row * LSTR + q * 32;
#pragma unroll
            for (int c = 0; c < 8; ++c) {
                float4 v = src[c];
                unsigned int p0 = (unsigned int)f2bf(v.x) | ((unsigned int)f2bf(v.y) << 16);
                unsigned int p1 = (unsigned int)f2bf(v.z) | ((unsigned int)f2bf(v.w) << 16);
                *reinterpret_cast<uint2*>(dst + c * 4) = make_uint2(p0, p1);
            }
        }
        // ---- per-edge geometry ----
        if (tid < 64) {
            int e = lds_eid[tid];
            float x = r_iI[e * 3 + 0], y = r_iI[e * 3 + 1], z = r_iI[e * 3 + 2];
            float d = sqrtf(x * x + y * y + z * z + 3e-8f);
            lds_dist[tid] = d;
            float inv_d = 1.0f / d;
            lds_unit[tid][0] = x * inv_d;
            lds_unit[tid][1] = y * inv_d;
            lds_unit[tid][2] = z * inv_d;
            float env = (d < CUTF) ? 0.5f * (__cosf(PI_F * d / CUTF) + 1.0f) : 0.0f;
            lds_env[tid] = (tid < valid) ? env : 0.0f;   // mask padded rows
        }
        __syncthreads();

        // ---- GEMM1: H = silu(S @ W1 + b1), H written in-place over S ----
        bf16x8 a1[4];
#pragma unroll
        for (int kt = 0; kt < 4; ++kt)
            a1[kt] = *reinterpret_cast<const bf16x8*>(
                lds_sh + (w * 16 + lc) * LSTR + kt * 32 + lq * 8);

#pragma unroll
        for (int nt = 0; nt < 8; ++nt) {
            f32x4 acc = {0.f, 0.f, 0.f, 0.f};
#pragma unroll
            for (int kt = 0; kt < 4; ++kt)
                acc = __builtin_amdgcn_mfma_f32_16x16x32_bf16(
                    a1[kt], W1f[(kt * 8 + nt) * 64 + lane], acc, 0, 0, 0);
#pragma unroll
            for (int i = 0; i < 4; ++i) {
                float x = acc[i] + b1v[nt];
                float h = x / (1.0f + __expf(-x));
                lds_sh[(w * 16 + lq * 4 + i) * LSTR + nt * 16 + lc] = (short)f2bf(h);
            }
        }
        // rows are wave-private; intra-wave LDS ordering is program order.

        // ---- GEMM2 A-fragments + rbf fragment ----
        bf16x8 a2[4];
#pragma unroll
        for (int kt = 0; kt < 4; ++kt)
            a2[kt] = *reinterpret_cast<const bf16x8*>(
                lds_sh + (w * 16 + lc) * LSTR + kt * 32 + lq * 8);

        bf16x8 rb;
        {
            float d = lds_dist[w * 16 + lc];
            float inv_d = 1.0f / d;
            float x0 = PI_F * d / CUTF;
#pragma unroll
            for (int j = 0; j < 8; ++j) {
                int k = lq * 8 + j;
                float v = 0.0f;
                if (k < NRBF) v = __sinf((float)(k + 1) * x0) * inv_d;
                rb[j] = (short)f2bf(v);
            }
        }

        // per-accumulator-row geometry: edge row = w*16 + lq*4 + i
        int   ei[4]; float envi[4], ux[4], uy[4], uz[4];
#pragma unroll
        for (int i = 0; i < 4; ++i) {
            int e = w * 16 + lq * 4 + i;
            ei[i]   = lds_eid[e];
            envi[i] = lds_env[e];
            ux[i] = lds_unit[e][0]; uy[i] = lds_unit[e][1]; uz[i] = lds_unit[e][2];
        }

        float* aw = lds_acc + w * 512;

#pragma unroll 1          // ROLLED: 8x unroll spilled (VGPR 256, +1GB scratch traffic in R2)
        for (int ft = 0; ft < 8; ++ft) {
            f32x4 acc0 = {0.f,0.f,0.f,0.f}, acc1 = {0.f,0.f,0.f,0.f}, acc2 = {0.f,0.f,0.f,0.f};
#pragma unroll
            for (int kt = 0; kt < 4; ++kt) {
                bf16x8 a = a2[kt];
                acc0 = __builtin_amdgcn_mfma_f32_16x16x32_bf16(a, W2f[(kt * 24 + ft     ) * 64 + lane], acc0, 0, 0, 0);
                acc1 = __builtin_amdgcn_mfma_f32_16x16x32_bf16(a, W2f[(kt * 24 + ft +  8) * 64 + lane], acc1, 0, 0, 0);
                acc2 = __builtin_amdgcn_mfma_f32_16x16x32_bf16(a, W2f[(kt * 24 + ft + 16) * 64 + lane], acc2, 0, 0, 0);
            }
            f32x4 z4 = {0.f,0.f,0.f,0.f};
            f32x4 wa0 = __builtin_amdgcn_mfma_f32_16x16x32_bf16(rb, Wrf[(ft     ) * 64 + lane], z4, 0, 0, 0);
            f32x4 wa1 = __builtin_amdgcn_mfma_f32_16x16x32_bf16(rb, Wrf[(ft +  8) * 64 + lane], z4, 0, 0, 0);
            f32x4 wa2 = __builtin_amdgcn_mfma_f32_16x16x32_bf16(rb, Wrf[(ft + 16) * 64 + lane], z4, 0, 0, 0);

            int f = ft * 16 + lc;
            float b2v0 = b2[f], b2v1 = b2[128 + f], b2v2 = b2[256 + f];
            float brv0 = br[f], brv1 = br[128 + f], brv2 = br[256 + f];

            float sds = 0.f, svx = 0.f, svy = 0.f, svz = 0.f;
#pragma unroll
            for (int i = 0; i < 4; ++i) {
                float phi0 = acc0[i] + b2v0;
                float phi1 = acc1[i] + b2v1;
                float phi2 = acc2[i] + b2v2;
                float w0 = (wa0[i] + brv0) * envi[i];
                float w1 = (wa1[i] + brv1) * envi[i];
                float w2 = (wa2[i] + brv2) * envi[i];
                float inv0 = phi0 * w0;
                float inv1 = phi1 * w1;
                float inv2 = phi2 * w2;

                const float* vp = v_i + (size_t)ei[i] * 384 + f * 3;
                sds += inv1;
                svx += inv2 * ux[i] + inv0 * vp[0];
                svy += inv2 * uy[i] + inv0 * vp[1];
                svz += inv2 * uz[i] + inv0 * vp[2];
            }
            // reduce across the 4 quads (edge groups): lanes differ in lq only
            sds += __shfl_xor(sds, 16); sds += __shfl_xor(sds, 32);
            svx += __shfl_xor(svx, 16); svx += __shfl_xor(svx, 32);
            svy += __shfl_xor(svy, 16); svy += __shfl_xor(svy, 32);
            svz += __shfl_xor(svz, 16); svz += __shfl_xor(svz, 32);
            if (lq == 0) {
                aw[f]               += sds;
                aw[128 + f * 3 + 0] += svx;
                aw[128 + f * 3 + 1] += svy;
                aw[128 + f * 3 + 2] += svz;
            }
        }
    }
    __syncthreads();

    // ---- final: cross-wave reduce, mean, write out ----
    const float invc = (cnt > 0) ? (1.0f / (float)cnt) : 0.0f;
    const int NS = NCG * 128;
    for (int o = tid; o < 512; o += 256) {
        float v = lds_acc[o] + lds_acc[512 + o] + lds_acc[1024 + o] + lds_acc[1536 + o];
        v *= invc;
        if (o < 128) out[(size_t)seg * 128 + o] = v;
        else         out[NS + (size_t)seg * 384 + (o - 128)] = v;
    }
}

extern "C" void kernel_launch(void* const* d_in, const int* in_sizes, int n_in,
                              void* d_out, int out_size, void* d_ws, size_t ws_size,
                              hipStream_t stream) {
    const float* s_i  = (const float*)d_in[0];
    const float* v_i  = (const float*)d_in[1];
    const float* r_iI = (const float*)d_in[2];
    const float* W1   = (const float*)d_in[3];
    const float* b1   = (const float*)d_in[4];
    const float* W2   = (const float*)d_in[5];
    const float* b2   = (const float*)d_in[6];
    const float* Wr   = (const float*)d_in[7];
    const float* br   = (const float*)d_in[8];
    const int* mapping = (const int*)d_in[9];
    // d_in[10] = num_cg (compile-time NCG=2000)

    const int E = in_sizes[0] / FEATN;   // 200000

    char* ws = (char*)d_ws;
    int*   counts = (int*)(ws + 0);          //  8,000 B
    int*   start  = (int*)(ws + 8192);       //  8,000 B
    int*   cursor = (int*)(ws + 16384);      //  8,000 B
    int*   order  = (int*)(ws + 24576);      // 800,000 B
    short* W1p    = (short*)(ws + 829440);   // 32,768 B
    short* W2p    = (short*)(ws + 862208);   // 98,304 B
    short* Wrp    = (short*)(ws + 960512);   // 24,576 B

    hipMemsetAsync(counts, 0, NCG * sizeof(int), stream);
    pack_weights<<<(W1P_ELEMS + W2P_ELEMS + WRP_ELEMS) / 256, 256, 0, stream>>>(
        W1, W2, Wr, W1p, W2p, Wrp);
    hist_kernel<<<(E + 255) / 256, 256, 0, stream>>>(mapping, counts, E);
    scan_kernel<<<1, 64, 0, stream>>>(counts, start, cursor);
    scatter_kernel<<<(E + 255) / 256, 256, 0, stream>>>(mapping, cursor, order, E);
    main_kernel<<<NCG, 256, 0, stream>>>(s_i, v_i, r_iI, b1, b2, br,
                                         order, start, counts,
                                         W1p, W2p, Wrp, (float*)d_out);
}